// Round 2
// baseline (346.636 us; speedup 1.0000x reference)
//
#include <hip/hip_runtime.h>
#include <math.h>

#define NN 32768
#define EN 1048576
#define NBIN 512          // coarse bins: bin = rcv >> 6 (64 receivers per bin)
#define BINCAP 4096       // slots per bin (avg 2048, +45 sigma)
#define TILE 2048         // edges per bin_k block

// C = 1/sqrt(E[gelu(z)^2]) , E = 1/3 + 1/(2*pi*sqrt(3))
#define C_GELU_F 1.5335262f

// ---------------- pass A: coarse-bin edges, coalesced writes ----------------
// word = (rcv << 15) | snd  (30 bits); bin = word >> 21 = rcv >> 6.
// Also packs positions -> float4: 512 blocks x 64 nodes.
__global__ __launch_bounds__(512) void bin_k(const int* __restrict__ snd,
                                             const int* __restrict__ rcv,
                                             const float* __restrict__ pos,
                                             float4* __restrict__ posw,
                                             int* __restrict__ bin_cur,
                                             unsigned* __restrict__ binbuf) {
    __shared__ unsigned cnt[NBIN];
    __shared__ unsigned excl[NBIN];
    __shared__ unsigned cur2[NBIN];
    __shared__ unsigned gbase[NBIN];
    __shared__ unsigned stage[TILE];
    int t = threadIdx.x;
    int tile = blockIdx.x * TILE;
    cnt[t] = 0; cur2[t] = 0;
    if (t < 64) {                     // folded pos packing
        int n = (blockIdx.x << 6) + t;
        posw[n] = make_float4(pos[3*n], pos[3*n+1], pos[3*n+2], 0.f);
    }
    __syncthreads();

    unsigned w[TILE / 512];
#pragma unroll
    for (int i = 0; i < TILE / 512; ++i) {
        int e = tile + i * 512 + t;
        unsigned r = (unsigned)rcv[e], s = (unsigned)snd[e];
        w[i] = (r << 15) | s;
        atomicAdd(&cnt[w[i] >> 21], 1u);
    }
    __syncthreads();

    // Kogge-Stone over 512 counters -> exclusive scan
    unsigned my = cnt[t];
    excl[t] = my;
    __syncthreads();
    for (int d = 1; d < NBIN; d <<= 1) {
        unsigned v = (t >= d) ? excl[t - d] : 0u;
        __syncthreads();
        excl[t] += v;
        __syncthreads();
    }
    {
        unsigned myexcl = excl[t] - my;
        gbase[t] = atomicAdd((unsigned*)&bin_cur[t], my);
        excl[t] = myexcl;
    }
    __syncthreads();

#pragma unroll
    for (int i = 0; i < TILE / 512; ++i) {
        unsigned b = w[i] >> 21;
        unsigned p = excl[b] + atomicAdd(&cur2[b], 1u);
        stage[p] = w[i];
    }
    __syncthreads();

    for (int p = t; p < TILE; p += 512) {
        unsigned ww = stage[p];
        unsigned b = ww >> 21;
        unsigned idx = gbase[b] + ((unsigned)p - excl[b]);
        if (idx < BINCAP) binbuf[b * BINCAP + idx] = ww;
    }
}

// ---------------- pass B: per-bin counting sort -> CSR ----------------------
// Each block redundantly scans the 512 bin counts in LDS (cheap) for its base.
__global__ __launch_bounds__(512) void csr_k(const int* __restrict__ bin_cur,
                                             const unsigned* __restrict__ binbuf,
                                             int* __restrict__ row_ptr,
                                             int* __restrict__ edge_csr) {
    __shared__ unsigned sc[NBIN];
    __shared__ unsigned cnt[64];
    __shared__ unsigned excl[64];
    __shared__ unsigned cur2[64];
    int b = blockIdx.x;
    int t = threadIdx.x;

    sc[t] = (unsigned)bin_cur[t];
    __syncthreads();
    for (int d = 1; d < NBIN; d <<= 1) {
        unsigned v = (t >= d) ? sc[t - d] : 0u;
        __syncthreads();
        sc[t] += v;
        __syncthreads();
    }
    int Mraw = bin_cur[b];
    int base = (int)(sc[b] - (unsigned)Mraw);   // exclusive prefix = CSR base
    int M = Mraw > BINCAP ? BINCAP : Mraw;
    if (t < 64) { cnt[t] = 0; cur2[t] = 0; }
    __syncthreads();

    const unsigned* bb = binbuf + b * BINCAP;
    for (int i = t; i < M; i += 512)
        atomicAdd(&cnt[(bb[i] >> 15) & 63], 1u);
    __syncthreads();

    if (t < 64) excl[t] = cnt[t];
    __syncthreads();
    for (int d = 1; d < 64; d <<= 1) {
        unsigned v = (t >= d && t < 64) ? excl[t - d] : 0u;
        __syncthreads();
        if (t < 64) excl[t] += v;
        __syncthreads();
    }
    if (t < 64) {
        unsigned e = excl[t] - cnt[t];
        excl[t] = e;
        row_ptr[(b << 6) + t] = base + (int)e;
        if (b == NBIN - 1 && t == 63) row_ptr[NN] = base + (int)(e + cnt[63]);
    }
    __syncthreads();

    for (int i = t; i < M; i += 512) {
        unsigned ww = bb[i];
        unsigned r6 = (ww >> 15) & 63;
        unsigned dst = excl[r6] + atomicAdd(&cur2[r6], 1u);
        edge_csr[base + dst] = (int)(ww & 0x7FFF);
    }
}

// ---------------- fused aggregate + node update: ONE WAVE PER NODE ----------
// 64 lanes = (h in 0..3) x (j in 0..15); lane (h,j) owns agg[4h..4h+4)[j].
// Aggregation: every lane sees every edge -> no cross-lane reduce, wave-uniform
// trip count (cnt), one coalesced 64B x-row load per edge for the whole wave.
// Phase 3: w-split by h (q = 8 regs), p all-reduced via 2x shfl_xor; gelu runs
// lane-parallel through the (now free) sY scratch. Weights from L1 (26 KB,
// resident). LDS = sY only = 40960 B -> 4 blocks/CU. Zero __syncthreads.
#define BLK 512
#define YST 20                 // words per edge row (16B-aligned; 8-way wr conflict ok)
#define WROW (64 * YST)        // 1280 words per wave

__global__ __launch_bounds__(512, 8) void fused_k(const float* __restrict__ x,
                                                  const float4* __restrict__ posw,
                                                  const int* __restrict__ row_ptr,
                                                  const int* __restrict__ edge_csr,
                                                  const float* __restrict__ Wpre,
                                                  const float* __restrict__ Wpost,
                                                  const float* __restrict__ Wsc,
                                                  float* __restrict__ out) {
    __shared__ float sY[8 * WROW];   // 40960 B exactly -> 4 blocks/CU

    int t = threadIdx.x;
    int wv = t >> 6;
    int lane = t & 63;
    int h = lane >> 4;               // u-block 0..3
    int j = lane & 15;               // output slot 0..15
    int n = (blockIdx.x << 3) + wv;
    int beg = row_ptr[n], end = row_ptr[n + 1];
    int cnt = end - beg;
    float4 rp = posw[n];
    float* yg = sY + wv * WROW;

    const float s3   = 1.7320508075688772f;
    const float s5   = 2.2360679774997896f;
    const float s15  = 3.8729833462074170f;
    const float s7   = 2.6457513110645907f;
    const float s105 = 10.246950765959598f;
    const float s35_8 = 2.0916500663351889f;
    const float s21_8 = 1.6201851746019651f;

    float acc0 = 0.f, acc1 = 0.f, acc2 = 0.f, acc3 = 0.f;
    const float* xh = x + (h << 2);  // h's float4 within each 16-float row

    int nch = (cnt + 63) >> 6;
    for (int c = 0; c < nch; ++c) {
        int k = (c << 6) + lane;
        int ki = k < cnt ? k : cnt - 1;
        int sE = edge_csr[beg + ki];
        float4 sp = posw[sE];

        // ---- step A: my edge's SH, zero-scaled if tail-invalid ----
        float vx = rp.x - sp.x, vy = rp.y - sp.y, vz = rp.z - sp.z;
        float n2 = vx*vx + vy*vy + vz*vz;
        float inv;
        if (n2 > 0.f) {
            inv = rsqrtf(n2);
            inv = inv * (1.5f - 0.5f * n2 * inv * inv);   // Newton: ~exact f32
        } else inv = 0.f;
        float X = vx*inv, Y = vy*inv, Z = vz*inv;
        float XX = X*X, YY = Y*Y, ZZ = Z*Z;
        float m = (k < cnt) ? 1.f : 0.f;

        float* yr = yg + lane * YST;
        ((float4*)yr)[0] = make_float4(m, m*(s3*X), m*(s3*Y), m*(s3*Z));
        ((float4*)yr)[1] = make_float4(m*(s15*X*Y), m*(s15*Y*Z),
                                       m*(0.5f*s5*(3.f*ZZ - 1.f)), m*(s15*X*Z));
        ((float4*)yr)[2] = make_float4(m*(0.5f*s15*(XX - YY)),
                                       m*(s35_8*Y*(3.f*XX - YY)),
                                       m*(s105*X*Y*Z),
                                       m*(s21_8*Y*(5.f*ZZ - 1.f)));
        ((float4*)yr)[3] = make_float4(m*(0.5f*s7*Z*(5.f*ZZ - 3.f)),
                                       m*(s21_8*X*(5.f*ZZ - 1.f)),
                                       m*(0.5f*s105*Z*(XX - YY)),
                                       m*(s35_8*X*(XX - 3.f*YY)));

        // ---- step B: wave-uniform e-loop, no padding, no divergence ----
        int rem = cnt - (c << 6); if (rem > 64) rem = 64;
#pragma unroll 4
        for (int e = 0; e < rem; ++e) {
            int se = __shfl(sE, e, 64);               // broadcast edge e's sender
            float y = yg[e * YST + j];                // conflict-free (16 consec words)
            const float4* xp = (const float4*)(xh + (se << 4));
            float4 a = *xp;                           // wave: one 64B row, coalesced
            acc0 += a.x * y; acc1 += a.y * y;
            acc2 += a.z * y; acc3 += a.w * y;
        }
    }

    // ---- phase 3: per-(n,j) node update, w-split by h ----
    int l, i, offl, deg;
    if (j == 0)      { l = 0; i = 0;     offl = 0;   deg = 1; }
    else if (j < 4)  { l = 1; i = j - 1; offl = 32;  deg = 3; }
    else if (j < 9)  { l = 2; i = j - 4; offl = 128; deg = 5; }
    else             { l = 3; i = j - 9; offl = 288; deg = 7; }

    const float c1 = 0.0078125f;            // (1/DENOM) * inv_in
    const float c2 = 0.17677669529663687f;  // 1/sqrt(32)

    // partial p over my 4 u's, all 32 v's
    float p[32];
#pragma unroll
    for (int v = 0; v < 32; ++v) p[v] = 0.f;
    const float* wp = Wpre + ((l * 16 + (h << 2)) << 5);
#pragma unroll
    for (int u = 0; u < 4; ++u) {
        float a = (u == 0) ? acc0 : (u == 1) ? acc1 : (u == 2) ? acc2 : acc3;
        const float4* w4 = (const float4*)(wp + (u << 5));
#pragma unroll
        for (int vq = 0; vq < 8; ++vq) {
            float4 w = w4[vq];
            p[4*vq+0] += a * w.x;
            p[4*vq+1] += a * w.y;
            p[4*vq+2] += a * w.z;
            p[4*vq+3] += a * w.w;
        }
    }
    // all-reduce over h (xor 16, 32) -> every lane holds full p[32]
#pragma unroll
    for (int v = 0; v < 32; ++v) p[v] += __shfl_xor(p[v], 16, 64);
#pragma unroll
    for (int v = 0; v < 32; ++v) p[v] += __shfl_xor(p[v], 32, 64);
#pragma unroll
    for (int v = 0; v < 32; ++v) p[v] *= c1;

    // gelu on l=0's p: lane-parallel via sY scratch (one erf pass per node,
    // 32 lanes wide, instead of 32 serial erfs). In-wave DS ordering, no barrier.
    if (lane == 0) {
#pragma unroll
        for (int k8 = 0; k8 < 8; ++k8)
            ((float4*)yg)[k8] = make_float4(p[4*k8], p[4*k8+1], p[4*k8+2], p[4*k8+3]);
    }
    if (lane < 32) {
        float tv = yg[lane];
        tv = C_GELU_F * 0.5f * tv * (1.f + erff(tv * 0.7071067811865476f));
        yg[lane] = tv;
    }
    if (j == 0) {
#pragma unroll
        for (int k8 = 0; k8 < 8; ++k8) {
            float4 g = ((const float4*)yg)[k8];
            p[4*k8] = g.x; p[4*k8+1] = g.y; p[4*k8+2] = g.z; p[4*k8+3] = g.w;
        }
    }

    // q for my 8 w's (w = 8h + w8)
    float q[8];
#pragma unroll
    for (int w8 = 0; w8 < 8; ++w8) q[w8] = 0.f;
    const float* wq = Wpost + (l << 10) + (h << 3);
#pragma unroll
    for (int v = 0; v < 32; ++v) {
        float pv = p[v];
        const float4* w4 = (const float4*)(wq + (v << 5));
        float4 wa = w4[0], wb = w4[1];
        q[0] += pv * wa.x; q[1] += pv * wa.y;
        q[2] += pv * wa.z; q[3] += pv * wa.w;
        q[4] += pv * wb.x; q[5] += pv * wb.y;
        q[6] += pv * wb.z; q[7] += pv * wb.w;
    }
#pragma unroll
    for (int w8 = 0; w8 < 8; ++w8) q[w8] *= c2;

    if (j == 0) {   // shortcut: (x @ Wsc) * 1/4, only the 0e path, split by h
        const float* xr = x + (n << 4);
        const float* ws = Wsc + (h << 3);
#pragma unroll
        for (int u = 0; u < 16; ++u) {
            float xv = 0.25f * xr[u];
            const float4* w4 = (const float4*)(ws + (u << 5));
            float4 wa = w4[0], wb = w4[1];
            q[0] += xv * wa.x; q[1] += xv * wa.y;
            q[2] += xv * wa.z; q[3] += xv * wa.w;
            q[4] += xv * wb.x; q[5] += xv * wb.y;
            q[6] += xv * wb.z; q[7] += xv * wb.w;
        }
    }

    float* op = out + (n << 9) + offl + i + ((h << 3) * deg);
#pragma unroll
    for (int w8 = 0; w8 < 8; ++w8) op[w8 * deg] = q[w8];
}

extern "C" void kernel_launch(void* const* d_in, const int* in_sizes, int n_in,
                              void* d_out, int out_size, void* d_ws, size_t ws_size,
                              hipStream_t stream) {
    const float* x     = (const float*)d_in[0];
    const float* pos   = (const float*)d_in[1];
    const float* Wpre  = (const float*)d_in[2];
    const float* Wpost = (const float*)d_in[3];
    const float* Wsc   = (const float*)d_in[4];
    const int*   snd   = (const int*)d_in[5];
    const int*   rcv   = (const int*)d_in[6];
    float* out = (float*)d_out;

    char* ws = (char*)d_ws;
    int*      bin_cur   = (int*)(ws);                    // 2 KiB
    int*      row_ptr   = (int*)(ws + 2048);             // 128 KiB + 4
    float4*   posw      = (float4*)(ws + 0x30000);       // 512 KiB
    int*      edge_csr  = (int*)(ws + 0xB0000);          // 4 MiB
    unsigned* binbuf    = (unsigned*)(ws + 0x500000);    // 8 MiB

    hipMemsetAsync(bin_cur, 0, NBIN * sizeof(int), stream);
    bin_k<<<EN / TILE, 512, 0, stream>>>(snd, rcv, pos, posw, bin_cur, binbuf);
    csr_k<<<NBIN, 512, 0, stream>>>(bin_cur, binbuf, row_ptr, edge_csr);
    fused_k<<<NN / 8, BLK, 0, stream>>>(x, posw, row_ptr, edge_csr,
                                        Wpre, Wpost, Wsc, out);
}